// Round 4
// baseline (80.530 us; speedup 1.0000x reference)
//
#include <hip/hip_runtime.h>
#include <math.h>

// Problem constants (from the reference file)
constexpr int B_   = 128;
constexpr int S_   = 2048;
constexpr int EMB_ = 128;
constexpr int HID_ = 256;
constexpr int OUT_ = 32;

constexpr int HT   = 8;         // h per block (per direction)
constexpr int BH   = 64;        // b per block (half the batch)
constexpr int PADK = EMB_ + 4;  // 132: 16B-aligned rows, stride%32==4 -> conflict-free b128
constexpr int NBLK = 128;       // 2 dirs x 32 h-tiles x 2 b-halves

// ws layout:
//   [0, 1MB)   : partial logits pl[b][o][64]  (pidx = dir*32 + ht)
//   [1MB]      : uint32 arrival counter (never initialized: modulo trick)
constexpr size_t CTR_OFF = 1ull << 20;

// ---------------------------------------------------------------------------
// Single fused kernel. Each block: gates GEMV tile (as round 3) -> partial
// logits -> device-scope arrival; the 128th arriver reduces partials, adds
// by, and does the log-softmax for all 128 batch rows.
__global__ __launch_bounds__(512, 2) void bilstm_one(
    const int*   __restrict__ inputs,
    const float* __restrict__ weight,
    const float* __restrict__ Wxf, const float* __restrict__ bxf, const float* __restrict__ bhf,
    const float* __restrict__ Wxb, const float* __restrict__ bxb, const float* __restrict__ bhb,
    const float* __restrict__ Why, const float* __restrict__ by,
    float*       __restrict__ pl,          // [B][OUT][64]
    unsigned int* __restrict__ ctr,
    float*       __restrict__ out)
{
    __shared__ __align__(16) float Xs[BH][PADK];      // 33.8 KB
    __shared__ __align__(16) float Ws[3][HT][PADK];   // 12.7 KB
    __shared__ int   toks[BH];
    __shared__ float hy_s[BH][HT];                    // 2 KB   (flat == tid)
    __shared__ float Whys[OUT_][9];                   // 1.2 KB (pad 9: conflict-free)
    __shared__ __align__(16) float lg[B_][OUT_];      // 16 KB  (tail only)
    __shared__ float m_s[B_], s_s[B_];
    __shared__ int   is_last;

    const int blk   = blockIdx.x;
    const int dir   = blk >> 6;          // 64 blocks per direction
    const int ht    = (blk & 63) >> 1;   // 0..31
    const int bhalf = blk & 1;
    const int h0    = ht * HT;
    const int tid   = threadIdx.x;

    if (tid < BH)
        toks[tid] = inputs[(size_t)(bhalf * BH + tid) * S_ + (dir ? 0 : (S_ - 1))];
    __syncthreads();

    // ---- stage X: 64 rows x 32 float4, 4 passes of 512
    #pragma unroll
    for (int p = 0; p < 4; ++p) {
        const int idx = p * 512 + tid;
        const int bl  = idx >> 5;
        const int j   = idx & 31;
        const float4 v = reinterpret_cast<const float4*>(weight + (size_t)toks[bl] * EMB_)[j];
        *reinterpret_cast<float4*>(&Xs[bl][4 * j]) = v;
    }
    // ---- stage W: 3 gates x 8 rows x 32 float4
    {
        const float* Wx = dir ? Wxb : Wxf;
        for (int idx = tid; idx < 3 * HT * 32; idx += 512) {
            const int g   = idx >> 8;
            const int rem = idx & 255;
            const int hl  = rem >> 5;
            const int j   = rem & 31;
            const int grow = (g == 0) ? 0 : ((g == 1) ? 2 : 3);  // i, g, o rows
            const float4 v = reinterpret_cast<const float4*>(
                Wx + (size_t)(grow * HID_ + h0 + hl) * EMB_)[j];
            *reinterpret_cast<float4*>(&Ws[g][hl][4 * j]) = v;
        }
    }
    // ---- stage Why tile: [32 o][8 hl]
    if (tid < OUT_ * HT) {
        const int o  = tid >> 3;
        const int hl = tid & 7;
        Whys[o][hl] = Why[(size_t)o * HID_ + h0 + hl];
    }
    __syncthreads();

    // ---- gates: thread = (hl, bg)
    {
        const int hl = tid & (HT - 1);
        const int bg = tid >> 3;
        const int h  = h0 + hl;
        const float* bx = dir ? bxb : bxf;
        const float* bh = dir ? bhb : bhf;
        float gi = bx[h]            + bh[h];
        float gg = bx[2 * HID_ + h] + bh[2 * HID_ + h];
        float go = bx[3 * HID_ + h] + bh[3 * HID_ + h];

        #pragma unroll 8
        for (int k4 = 0; k4 < EMB_ / 4; ++k4) {
            const float4 x  = *reinterpret_cast<const float4*>(&Xs[bg][4 * k4]);
            const float4 wi = *reinterpret_cast<const float4*>(&Ws[0][hl][4 * k4]);
            const float4 wg = *reinterpret_cast<const float4*>(&Ws[1][hl][4 * k4]);
            const float4 wo = *reinterpret_cast<const float4*>(&Ws[2][hl][4 * k4]);
            gi = fmaf(x.x, wi.x, fmaf(x.y, wi.y, fmaf(x.z, wi.z, fmaf(x.w, wi.w, gi))));
            gg = fmaf(x.x, wg.x, fmaf(x.y, wg.y, fmaf(x.z, wg.z, fmaf(x.w, wg.w, gg))));
            go = fmaf(x.x, wo.x, fmaf(x.y, wo.y, fmaf(x.z, wo.z, fmaf(x.w, wo.w, go))));
        }
        const float si = 1.0f / (1.0f + expf(-gi));
        const float so = 1.0f / (1.0f + expf(-go));
        hy_s[bg][hl] = so * tanhf(si * tanhf(gg));   // flat index == tid
    }
    __syncthreads();

    // ---- partial logits: 4 (b,o) pairs per thread, dot over 8 h
    {
        const int pidx = dir * 32 + ht;
        #pragma unroll
        for (int i = 0; i < 4; ++i) {
            const int p = tid + 512 * i;
            const int b = p >> 5;            // 0..63 (bg)
            const int o = p & 31;
            float acc = 0.0f;
            #pragma unroll
            for (int hl = 0; hl < HT; ++hl)
                acc = fmaf(hy_s[b][hl], Whys[o][hl], acc);
            pl[(((size_t)(bhalf * BH + b)) * OUT_ + o) * 64 + pidx] = acc;
        }
    }

    // ---- arrival: release fence + device-scope atomic; 128th arriver tails
    __threadfence();
    if (tid == 0) {
        const unsigned int old = atomicAdd(ctr, 1u);
        is_last = ((old & (NBLK - 1)) == (NBLK - 1)) ? 1 : 0;
        __threadfence();   // acquire for the tail reads
    }
    __syncthreads();
    if (!is_last) return;

    // ---- tail: reduce 64 partials per (b,o), add by, log-softmax
    #pragma unroll
    for (int i = 0; i < 8; ++i) {
        const int q = tid + 512 * i;         // 0..4095
        const int b = q >> 5;
        const int o = q & 31;
        const float4* v = reinterpret_cast<const float4*>(pl + (size_t)q * 64);
        float4 a0 = v[0];
        #pragma unroll
        for (int j = 1; j < 16; ++j) {
            const float4 vv = v[j];
            a0.x += vv.x; a0.y += vv.y; a0.z += vv.z; a0.w += vv.w;
        }
        lg[b][o] = (a0.x + a0.y) + (a0.z + a0.w) + by[o];
    }
    __syncthreads();
    if (tid < B_) {
        float m = -1e30f;
        #pragma unroll 8
        for (int o = 0; o < OUT_; ++o) m = fmaxf(m, lg[tid][o]);
        float s = 0.0f;
        #pragma unroll 8
        for (int o = 0; o < OUT_; ++o) s += expf(lg[tid][o] - m);
        m_s[tid] = m;
        s_s[tid] = logf(s);
    }
    __syncthreads();
    #pragma unroll
    for (int i = 0; i < 8; ++i) {
        const int q = tid + 512 * i;
        const int b = q >> 5;
        const int o = q & 31;
        out[q] = lg[b][o] - m_s[b] - s_s[b];
    }
}

extern "C" void kernel_launch(void* const* d_in, const int* in_sizes, int n_in,
                              void* d_out, int out_size, void* d_ws, size_t ws_size,
                              hipStream_t stream) {
    // setup_inputs() order:
    // 0 inputs [B,S] int32      1 weight [VOCAB,EMB] f32
    // 2 Wxf [1024,128]  3 bxf [1024]  4 Whf (dead)  5 bhf [1024]
    // 6 Wxb [1024,128]  7 bxb [1024]  8 Whb (dead)  9 bhb [1024]
    // 10 Why [32,256]   11 by [32]
    const int*   inputs = (const int*)  d_in[0];
    const float* weight = (const float*)d_in[1];
    const float* Wxf    = (const float*)d_in[2];
    const float* bxf    = (const float*)d_in[3];
    const float* bhf    = (const float*)d_in[5];
    const float* Wxb    = (const float*)d_in[6];
    const float* bxb    = (const float*)d_in[7];
    const float* bhb    = (const float*)d_in[9];
    const float* Why    = (const float*)d_in[10];
    const float* by     = (const float*)d_in[11];
    float* out = (float*)d_out;

    float*        pl  = (float*)d_ws;
    unsigned int* ctr = (unsigned int*)((char*)d_ws + CTR_OFF);

    bilstm_one<<<NBLK, 512, 0, stream>>>(inputs, weight,
                                         Wxf, bxf, bhf,
                                         Wxb, bxb, bhb,
                                         Why, by, pl, ctr, out);
}

// Round 5
// 37.548 us; speedup vs baseline: 2.1447x; 2.1447x over previous
//
#include <hip/hip_runtime.h>
#include <math.h>

// Problem constants (from the reference file)
constexpr int B_   = 128;
constexpr int S_   = 2048;
constexpr int EMB_ = 128;
constexpr int HID_ = 256;
constexpr int OUT_ = 32;

constexpr int HT   = 64;        // h per block
constexpr int BT   = 16;        // b per block
constexpr int NBLK = 64;        // 2 dir x 4 h-tiles x 8 b-tiles
constexpr int PADK = EMB_ + 4;  // 132: 16B-aligned rows, bank stride 4
constexpr int PWHY = HT + 4;    // 68: 272 B rows, 16B-aligned

// ws layout:
//   [0, 128KB) : partial logits pl[b][o][8]   (pidx = dir*4 + ht)
//   [1MB]      : uint32 arrival counter (memset to 0 every call)
constexpr size_t CTR_OFF = 1ull << 20;

// ---------------------------------------------------------------------------
// Single fused kernel. Block (dir, ht, bq): 64-h x 16-b gates tile ->
// partial logits -> device-scope arrival; the exact 64th arriver reduces the
// 8 partials per (b,o), adds by, and does the 32-wide log-softmax.
__global__ __launch_bounds__(512, 1) void bilstm_one(
    const int*   __restrict__ inputs,
    const float* __restrict__ weight,
    const float* __restrict__ Wxf, const float* __restrict__ bxf, const float* __restrict__ bhf,
    const float* __restrict__ Wxb, const float* __restrict__ bxb, const float* __restrict__ bhb,
    const float* __restrict__ Why, const float* __restrict__ by,
    float*        __restrict__ pl,          // [B][OUT][8]
    unsigned int* __restrict__ ctr,
    float*        __restrict__ out)
{
    __shared__ __align__(16) float Xs[BT][PADK];       //   8.4 KB
    __shared__ __align__(16) float Ws[3][HT][PADK];    // 101.4 KB
    __shared__ __align__(16) float Whys[OUT_][PWHY];   //   8.7 KB
    __shared__ float hy_s[BT][HT];                     //   4.0 KB
    __shared__ int   toks[BT];
    __shared__ __align__(16) float lg[B_][OUT_];       //  16.4 KB (tail only)
    __shared__ float m_s[B_], s_s[B_];
    __shared__ int   is_last;

    const int blk = blockIdx.x;
    const int dir = blk >> 5;            // 0,1
    const int ht  = (blk >> 3) & 3;      // 0..3
    const int bq  = blk & 7;             // 0..7
    const int h0  = ht * HT;
    const int b0  = bq * BT;
    const int tid = threadIdx.x;

    if (tid < BT)
        toks[tid] = inputs[(size_t)(b0 + tid) * S_ + (dir ? 0 : (S_ - 1))];
    __syncthreads();

    // ---- stage X: 16 rows x 32 float4 = 512 float4, one per thread
    {
        const int r = tid >> 5, c = tid & 31;
        const float4 v = reinterpret_cast<const float4*>(weight + (size_t)toks[r] * EMB_)[c];
        *reinterpret_cast<float4*>(&Xs[r][4 * c]) = v;
    }
    // ---- stage W: 3 gates x 64 rows x 32 float4 = 6144 float4, 12/thread
    {
        const float* Wx = dir ? Wxb : Wxf;
        #pragma unroll
        for (int j = 0; j < 12; ++j) {
            const int idx = tid + 512 * j;     // 0..6143
            const int r   = idx >> 5;          // 0..191
            const int c   = idx & 31;
            const int g   = r >> 6;            // 0..2
            const int hl  = r & 63;
            const int grow = (g == 0) ? 0 : (g + 1);   // gate rows: i->0, g->2, o->3
            const float4 v = reinterpret_cast<const float4*>(
                Wx + (size_t)(grow * HID_ + h0 + hl) * EMB_)[c];
            *reinterpret_cast<float4*>(&Ws[g][hl][4 * c]) = v;
        }
    }
    // ---- stage Why tile: 32 o x 16 float4 (64 h), one per thread
    {
        const int o = tid >> 4, c = tid & 15;
        const float4 v = reinterpret_cast<const float4*>(Why + (size_t)o * HID_ + h0)[c];
        *reinterpret_cast<float4*>(&Whys[o][4 * c]) = v;
    }
    __syncthreads();

    // ---- gates: wave = (h-half, b-quad), thread = 1 h x 2 b
    {
        const int wave = tid >> 6;
        const int lane = tid & 63;
        const int wh   = wave & 1;               // h-half 0,1
        const int wb   = wave >> 1;              // b-quad 0..3
        const int hloc = wh * 32 + (lane & 31);  // 0..63
        const int bl0  = wb * 4 + (lane >> 5) * 2;  // 0..14 (even)
        const int h    = h0 + hloc;

        const float* bx = dir ? bxb : bxf;
        const float* bh = dir ? bhb : bhf;
        const float bi = bx[h]            + bh[h];
        const float bg = bx[2 * HID_ + h] + bh[2 * HID_ + h];
        const float bo = bx[3 * HID_ + h] + bh[3 * HID_ + h];

        float i0 = bi, g0 = bg, o0 = bo;
        float i1 = bi, g1 = bg, o1 = bo;

        #pragma unroll 8
        for (int k4 = 0; k4 < EMB_ / 4; ++k4) {
            const float4 wi = *reinterpret_cast<const float4*>(&Ws[0][hloc][4 * k4]);
            const float4 wg = *reinterpret_cast<const float4*>(&Ws[1][hloc][4 * k4]);
            const float4 wo = *reinterpret_cast<const float4*>(&Ws[2][hloc][4 * k4]);
            const float4 x0 = *reinterpret_cast<const float4*>(&Xs[bl0][4 * k4]);
            const float4 x1 = *reinterpret_cast<const float4*>(&Xs[bl0 + 1][4 * k4]);
            i0 = fmaf(x0.x, wi.x, fmaf(x0.y, wi.y, fmaf(x0.z, wi.z, fmaf(x0.w, wi.w, i0))));
            g0 = fmaf(x0.x, wg.x, fmaf(x0.y, wg.y, fmaf(x0.z, wg.z, fmaf(x0.w, wg.w, g0))));
            o0 = fmaf(x0.x, wo.x, fmaf(x0.y, wo.y, fmaf(x0.z, wo.z, fmaf(x0.w, wo.w, o0))));
            i1 = fmaf(x1.x, wi.x, fmaf(x1.y, wi.y, fmaf(x1.z, wi.z, fmaf(x1.w, wi.w, i1))));
            g1 = fmaf(x1.x, wg.x, fmaf(x1.y, wg.y, fmaf(x1.z, wg.z, fmaf(x1.w, wg.w, g1))));
            o1 = fmaf(x1.x, wo.x, fmaf(x1.y, wo.y, fmaf(x1.z, wo.z, fmaf(x1.w, wo.w, o1))));
        }

        const float si0 = 1.0f / (1.0f + expf(-i0));
        const float so0 = 1.0f / (1.0f + expf(-o0));
        const float si1 = 1.0f / (1.0f + expf(-i1));
        const float so1 = 1.0f / (1.0f + expf(-o1));
        hy_s[bl0][hloc]     = so0 * tanhf(si0 * tanhf(g0));
        hy_s[bl0 + 1][hloc] = so1 * tanhf(si1 * tanhf(g1));
    }
    __syncthreads();

    // ---- partial logits: thread = one (b,o) pair, dot over 64 h
    {
        const int bl = tid >> 5;         // 0..15
        const int o  = tid & 31;
        float acc = 0.0f;
        #pragma unroll 8
        for (int hl = 0; hl < HT; ++hl)
            acc = fmaf(hy_s[bl][hl], Whys[o][hl], acc);
        const int pidx = dir * 4 + ht;   // 0..7
        pl[((size_t)(b0 + bl) * OUT_ + o) * 8 + pidx] = acc;
    }

    // ---- arrival: release fence + device-scope atomic; 64th arriver tails
    __threadfence();
    if (tid == 0) {
        const unsigned int old = atomicAdd(ctr, 1u);
        is_last = (old == NBLK - 1) ? 1 : 0;   // ctr memset to 0 every call
        __threadfence();                        // acquire for the tail reads
    }
    __syncthreads();
    if (!is_last) return;

    // ---- tail: reduce 8 partials per (b,o) (128 KB), add by, log-softmax
    #pragma unroll
    for (int i = 0; i < 8; ++i) {
        const int q = tid + 512 * i;     // 0..4095
        const float4* v = reinterpret_cast<const float4*>(pl + (size_t)q * 8);
        const float4 a = v[0];
        const float4 c = v[1];
        lg[q >> 5][q & 31] = ((a.x + a.y) + (a.z + a.w))
                           + ((c.x + c.y) + (c.z + c.w)) + by[q & 31];
    }
    __syncthreads();
    if (tid < B_) {
        float m = -1e30f;
        #pragma unroll 8
        for (int o = 0; o < OUT_; ++o) m = fmaxf(m, lg[tid][o]);
        float s = 0.0f;
        #pragma unroll 8
        for (int o = 0; o < OUT_; ++o) s += expf(lg[tid][o] - m);
        m_s[tid] = m;
        s_s[tid] = logf(s);
    }
    __syncthreads();
    #pragma unroll
    for (int i = 0; i < 8; ++i) {
        const int q = tid + 512 * i;
        out[q] = lg[q >> 5][q & 31] - m_s[q >> 5] - s_s[q >> 5];
    }
}

extern "C" void kernel_launch(void* const* d_in, const int* in_sizes, int n_in,
                              void* d_out, int out_size, void* d_ws, size_t ws_size,
                              hipStream_t stream) {
    // setup_inputs() order:
    // 0 inputs [B,S] int32      1 weight [VOCAB,EMB] f32
    // 2 Wxf [1024,128]  3 bxf [1024]  4 Whf (dead)  5 bhf [1024]
    // 6 Wxb [1024,128]  7 bxb [1024]  8 Whb (dead)  9 bhb [1024]
    // 10 Why [32,256]   11 by [32]
    const int*   inputs = (const int*)  d_in[0];
    const float* weight = (const float*)d_in[1];
    const float* Wxf    = (const float*)d_in[2];
    const float* bxf    = (const float*)d_in[3];
    const float* bhf    = (const float*)d_in[5];
    const float* Wxb    = (const float*)d_in[6];
    const float* bxb    = (const float*)d_in[7];
    const float* bhb    = (const float*)d_in[9];
    const float* Why    = (const float*)d_in[10];
    const float* by     = (const float*)d_in[11];
    float* out = (float*)d_out;

    float*        pl  = (float*)d_ws;
    unsigned int* ctr = (unsigned int*)((char*)d_ws + CTR_OFF);

    // Exact-arrival counter: zero it every call (captures as a memset node).
    hipMemsetAsync(ctr, 0, sizeof(unsigned int), stream);

    bilstm_one<<<NBLK, 512, 0, stream>>>(inputs, weight,
                                         Wxf, bxf, bhf,
                                         Wxb, bxb, bhb,
                                         Why, by, pl, ctr, out);
}